// Round 13
// baseline (259.288 us; speedup 1.0000x reference)
//
#include <hip/hip_runtime.h>

typedef float    f32x4 __attribute__((ext_vector_type(4)));
typedef _Float16 f16x8 __attribute__((ext_vector_type(8)));
typedef _Float16 f16x4 __attribute__((ext_vector_type(4)));
typedef _Float16 f16;

#define DEVFN static __device__ __forceinline__

constexpr int BB = 2, SS = 4096, DD = 1024;
constexpr int MROWS = BB * SS; // 8192

// ---------------- workspace layout (bytes) ----------------
constexpr size_t SZ_QK   = (size_t)MROWS * DD * 2;
constexpr size_t SZ_VT   = (size_t)BB * DD * SS * 2;
constexpr size_t SZ_ATTN = (size_t)BB * SS * SS * 2;
constexpr size_t SZ_S    = (size_t)BB * SS * SS * 4;
constexpr size_t SZ_W    = (size_t)DD * DD * 2;

constexpr size_t O_VT   = 0;
constexpr size_t O_ATTN = O_VT + SZ_VT;
constexpr size_t O_Q    = O_ATTN;            // Q fp16, dead after scores
constexpr size_t O_K    = O_Q + 2 * SZ_QK;   // K fp16, dead after scores
constexpr size_t O_S    = O_ATTN + SZ_ATTN;  // f32 scores
constexpr size_t O_XH   = O_S;               // phase-1 aliases in scores region
constexpr size_t O_WQH  = O_XH + SZ_QK;
constexpr size_t O_WKH  = O_WQH + SZ_W;
constexpr size_t O_WVH  = O_WKH + SZ_W;
constexpr size_t WS_NEEDED = SZ_VT + SZ_ATTN + SZ_S;

// ---------------- helpers ----------------
DEVFN f32x4 mfma16x16x32(f16x8 a, f16x8 b, f32x4 c) {
  return __builtin_amdgcn_mfma_f32_16x16x32_f16(a, b, c, 0, 0, 0);
}

DEVFN void gld16(const f16* g, char* l) {
  __builtin_amdgcn_global_load_lds((const __attribute__((address_space(1))) void*)g,
                                   (__attribute__((address_space(3))) void*)l, 16, 0, 0);
}

// bijective XCD-chunked block swizzle (requires total blocks % 8 == 0)
DEVFN void swz_xy(int& bx, int& by, int& bz) {
  const int gx = gridDim.x, gy = gridDim.y, gz = gridDim.z;
  const int lin = (blockIdx.z * gy + blockIdx.y) * gx + blockIdx.x;
  const int chunk = (gx * gy * gz) >> 3;
  const int nl = (lin & 7) * chunk + (lin >> 3);
  bx = nl % gx; const int r = nl / gx; by = r % gy; bz = r / gy;
}

// =====================================================================
// 256x128 8-phase GEMM core, DEEP A-prefetch.
// A: 3 buffers (32 KB), staged 2 tiles ahead (ph0/ph1) -> cover ~6-7
// phases (~1800 cyc > HBM 900). B: 2 buffers (16 KB), staged ph2.
// ONE vmcnt(4) per tile at ph1-end. LDS = 128 KiB.
// =====================================================================
DEVFN void gemm128_core(const f16* Ap, const f16* Bp, size_t ld, int NT,
                        char* smem, f32x4 (&acc)[4][4]) {
  const int tid = threadIdx.x, lane = tid & 63, wave = tid >> 6;
  const int wm = wave >> 1, wn = wave & 1;
  const size_t rk = (size_t)(tid >> 3) * ld +
                    (size_t)((((lane & 7) ^ (lane >> 3)) << 3));
  const int wvoff = wave << 10;
  const int rbA = (((wm << 6) + (lane & 15)) << 7);
  const int rbB = (((wn << 6) + (lane & 15)) << 7);
  const int cx0 = (((lane >> 4) << 4)) ^ ((lane & 7) << 4);
  const int cx1 = cx0 ^ 64;

  char* LA0 = smem;             // 32 KB
  char* LA1 = smem + 32768;     // 32 KB
  char* LA2 = smem + 65536;     // 32 KB
  char* LB0 = smem + 98304;     // 16 KB
  char* LB1 = smem + 114688;    // 16 KB

  auto stA = [&](int u, int q, char* dst) {
    int uc = (u < NT) ? u : (NT - 1);
    gld16(Ap + (size_t)(q << 6) * ld + ((size_t)uc << 6) + rk, dst + (q << 13) + wvoff);
  };
  auto stB = [&](int u, int q, char* dst) {
    int uc = (u < NT) ? u : (NT - 1);
    gld16(Bp + (size_t)(q << 6) * ld + ((size_t)uc << 6) + rk, dst + (q << 13) + wvoff);
  };
  auto rdA = [&](char* l, int m, int cx) { return *(const f16x8*)(l + rbA + (m << 11) + cx); };
  auto rdB = [&](char* l, int n, int cx) { return *(const f16x8*)(l + rbB + (n << 11) + cx); };

  f16x8 A0[2][2], B0[2][2], A0n[2][2], B0n[2][2];

  // ---- prologue: A(0),B(0),A(1),B(1) = 12 loads; keep newest 6 in flight ----
  stA(0, 0, LA0); stA(0, 1, LA0); stA(0, 2, LA0); stA(0, 3, LA0);
  stB(0, 0, LB0); stB(0, 1, LB0);
  stA(1, 0, LA1); stA(1, 1, LA1); stA(1, 2, LA1); stA(1, 3, LA1);
  stB(1, 0, LB1); stB(1, 1, LB1);
  asm volatile("s_waitcnt vmcnt(6)" ::: "memory");
  __builtin_amdgcn_s_barrier();
#pragma unroll
  for (int n = 0; n < 2; ++n) { B0[n][0] = rdB(LB0, n, cx0); B0[n][1] = rdB(LB0, n, cx1); }
#pragma unroll
  for (int m = 0; m < 2; ++m) { A0[m][0] = rdA(LA0, m, cx0); A0[m][1] = rdA(LA0, m, cx1); }

  char *aC = LA0, *aN = LA1, *aN2 = LA2, *bC = LB0, *bN = LB1;

  auto tileX = [&](char* lA, char* lB, char* lAn, char* lA2, char* lBn, int t,
                   f16x8 (&a0)[2][2], f16x8 (&b0)[2][2],
                   f16x8 (&a0n)[2][2], f16x8 (&b0n)[2][2]) {
    f16x8 a1[2][2], b1[2][2];
    // ---- ph0: read b1(cur); stage A(t+2)q0,q1; MFMA a0*b0 ----
#pragma unroll
    for (int n = 0; n < 2; ++n) { b1[n][0] = rdB(lB, n + 2, cx0); b1[n][1] = rdB(lB, n + 2, cx1); }
    stA(t + 2, 0, lA2); stA(t + 2, 1, lA2);
    __builtin_amdgcn_s_barrier();
    asm volatile("s_waitcnt lgkmcnt(4)" ::: "memory");
    __builtin_amdgcn_sched_barrier(0);
    __builtin_amdgcn_s_setprio(1);
#pragma unroll
    for (int m = 0; m < 2; ++m)
#pragma unroll
      for (int n = 0; n < 2; ++n) {
        acc[m][n] = mfma16x16x32(a0[m][0], b0[n][0], acc[m][n]);
        acc[m][n] = mfma16x16x32(a0[m][1], b0[n][1], acc[m][n]);
      }
    __builtin_amdgcn_s_setprio(0);
    __builtin_amdgcn_s_barrier();
    // ---- ph1: read a1(cur); stage A(t+2)q2,q3; vmcnt(4); MFMA a0*b1 ----
#pragma unroll
    for (int m = 0; m < 2; ++m) { a1[m][0] = rdA(lA, m + 2, cx0); a1[m][1] = rdA(lA, m + 2, cx1); }
    stA(t + 2, 2, lA2); stA(t + 2, 3, lA2);
    asm volatile("s_waitcnt vmcnt(4)" ::: "memory");
    __builtin_amdgcn_s_barrier();
    asm volatile("s_waitcnt lgkmcnt(4)" ::: "memory");
    __builtin_amdgcn_sched_barrier(0);
    __builtin_amdgcn_s_setprio(1);
#pragma unroll
    for (int m = 0; m < 2; ++m)
#pragma unroll
      for (int n = 0; n < 2; ++n) {
        acc[m][n + 2] = mfma16x16x32(a0[m][0], b1[n][0], acc[m][n + 2]);
        acc[m][n + 2] = mfma16x16x32(a0[m][1], b1[n][1], acc[m][n + 2]);
      }
    __builtin_amdgcn_s_setprio(0);
    __builtin_amdgcn_s_barrier();
    // ---- ph2: read b0'(B(t+1)); stage B(t+2) -> lB; MFMA a1*b0 ----
#pragma unroll
    for (int n = 0; n < 2; ++n) { b0n[n][0] = rdB(lBn, n, cx0); b0n[n][1] = rdB(lBn, n, cx1); }
    stB(t + 2, 0, lB); stB(t + 2, 1, lB);
    __builtin_amdgcn_s_barrier();
    asm volatile("s_waitcnt lgkmcnt(4)" ::: "memory");
    __builtin_amdgcn_sched_barrier(0);
    __builtin_amdgcn_s_setprio(1);
#pragma unroll
    for (int m = 0; m < 2; ++m)
#pragma unroll
      for (int n = 0; n < 2; ++n) {
        acc[m + 2][n] = mfma16x16x32(a1[m][0], b0[n][0], acc[m + 2][n]);
        acc[m + 2][n] = mfma16x16x32(a1[m][1], b0[n][1], acc[m + 2][n]);
      }
    __builtin_amdgcn_s_setprio(0);
    __builtin_amdgcn_s_barrier();
    // ---- ph3: read a0'(A(t+1)); MFMA a1*b1 ----
#pragma unroll
    for (int m = 0; m < 2; ++m) { a0n[m][0] = rdA(lAn, m, cx0); a0n[m][1] = rdA(lAn, m, cx1); }
    __builtin_amdgcn_s_barrier();
    asm volatile("s_waitcnt lgkmcnt(4)" ::: "memory");
    __builtin_amdgcn_sched_barrier(0);
    __builtin_amdgcn_s_setprio(1);
#pragma unroll
    for (int m = 0; m < 2; ++m)
#pragma unroll
      for (int n = 0; n < 2; ++n) {
        acc[m + 2][n + 2] = mfma16x16x32(a1[m][0], b1[n][0], acc[m + 2][n + 2]);
        acc[m + 2][n + 2] = mfma16x16x32(a1[m][1], b1[n][1], acc[m + 2][n + 2]);
      }
    __builtin_amdgcn_s_setprio(0);
    __builtin_amdgcn_s_barrier();
  };

  for (int t = 0; t < NT; t += 2) {
    tileX(aC, bC, aN, aN2, bN, t, A0, B0, A0n, B0n);
    { char* tmp = aC; aC = aN; aN = aN2; aN2 = tmp; }
    { char* tmp = bC; bC = bN; bN = tmp; }
    tileX(aC, bC, aN, aN2, bN, t + 1, A0n, B0n, A0, B0);
    { char* tmp = aC; aC = aN; aN = aN2; aN2 = tmp; }
    { char* tmp = bC; bC = bN; bN = tmp; }
  }
  asm volatile("s_waitcnt vmcnt(0)" ::: "memory");
}

// ---------------- scores = Q . K^T (1024 blocks, supertiled map) -----------
// Each XCD's 128-block chunk covers a 16bx x 8by region (8 MB working set
// vs 10 MB for the row-major map) -> better L2 reuse of Q and K.
__global__ __launch_bounds__(512, 2)
void gemm_sc128(const f16* __restrict__ Q, const f16* __restrict__ Kp,
                float* __restrict__ Sf) {
  extern __shared__ char smem[];
  const int lin = (blockIdx.z * 16 + blockIdx.y) * 32 + blockIdx.x; // 1024
  const int g = (lin & 7) * 128 + (lin >> 3);   // xcd-chunked rank
  const int bz = g >> 9;
  const int w = g & 511;
  const int t = w >> 7, s = w & 127;            // 4 supertiles of 16x8
  const int bx = (t & 1) * 16 + (s & 15);
  const int by = (t >> 1) * 8 + (s >> 4);
  const size_t zo = (size_t)bz * SS * DD;
  const int row0 = by * 256, col0 = bx * 128;
  f32x4 acc[4][4] = {};
  gemm128_core(Q + zo + (size_t)row0 * DD, Kp + zo + (size_t)col0 * DD,
               DD, 16, smem, acc);

  float* C = Sf + (size_t)bz * SS * SS;
  const int lane = threadIdx.x & 63, wave = threadIdx.x >> 6;
  const int wm = wave >> 1, wn = wave & 1;
#pragma unroll
  for (int m = 0; m < 4; ++m)
#pragma unroll
    for (int n = 0; n < 4; ++n) {
      int col = col0 + wn * 64 + n * 16 + (lane & 15);
      int rowb = row0 + wm * 64 + m * 16 + (lane >> 4) * 4;
#pragma unroll
      for (int j = 0; j < 4; ++j)
        C[(size_t)(rowb + j) * SS + col] = acc[m][n][j];
    }
}

// ---------------- merged Q/K projections + Vt (768 blocks, one dispatch) -------
// id < 512: Q/K projection tile; id >= 512: Vt = Wv . x^T tile.
__global__ __launch_bounds__(512, 2)
void gemm_projvt128(const f16* __restrict__ xh,
                    const f16* __restrict__ wqh, const f16* __restrict__ wkh,
                    const f16* __restrict__ wvh,
                    const float* __restrict__ bq, const float* __restrict__ bk,
                    const float* __restrict__ bvv,
                    f16* __restrict__ Q, f16* __restrict__ K,
                    f16* __restrict__ Vt) {
  extern __shared__ char smem[];
  const int lin = blockIdx.x;                 // 768
  const int id = (lin & 7) * 96 + (lin >> 3); // bijective xcd chunking
  const int lane = threadIdx.x & 63, wave = threadIdx.x >> 6;
  const int wm = wave >> 1, wn = wave & 1;
  f32x4 acc[4][4] = {};

  if (id < 512) {
    const int bx = id & 15, by = id >> 4;     // grid (16,32)
    const int row0 = by * 256;
    const bool isK = bx >= 8;
    const int col0 = (bx & 7) * 128;
    const f16* B0p = isK ? wkh : wqh;
    const float* bias = isK ? bk : bq;
    f16* CH = isK ? K : Q;
    gemm128_core(xh + (size_t)row0 * DD, B0p + (size_t)col0 * DD, DD, 16, smem, acc);
#pragma unroll
    for (int m = 0; m < 4; ++m)
#pragma unroll
      for (int n = 0; n < 4; ++n) {
        int col = col0 + wn * 64 + n * 16 + (lane & 15);
        float bvv2 = bias[col];
        int rowb = row0 + wm * 64 + m * 16 + (lane >> 4) * 4;
#pragma unroll
        for (int j = 0; j < 4; ++j)
          CH[(size_t)(rowb + j) * DD + col] = (f16)(acc[m][n][j] + bvv2);
      }
  } else {
    const int id2 = id - 512;                 // grid (64,4): bx over s, by over d
    const int bx = id2 & 63, by = id2 >> 6;
    const int row0 = by * 256, col0 = bx * 128;
    gemm128_core(wvh + (size_t)row0 * DD, xh + (size_t)col0 * DD, DD, 16, smem, acc);
#pragma unroll
    for (int m = 0; m < 4; ++m)
#pragma unroll
      for (int n = 0; n < 4; ++n) {
        int col = col0 + wn * 64 + n * 16 + (lane & 15);
        int batch = col >> 12, sl = col & 4095;
        int rowb = row0 + wm * 64 + m * 16 + (lane >> 4) * 4;
#pragma unroll
        for (int j = 0; j < 4; ++j) {
          float v = acc[m][n][j] + bvv[rowb + j];
          Vt[(size_t)batch * DD * SS + (size_t)(rowb + j) * SS + sl] = (f16)v;
        }
      }
  }
}

// ---------------- out = attn @ V (256 blocks) ----------------
__global__ __launch_bounds__(512, 2)
void gemm_pv128(const f16* __restrict__ Pb, const f16* __restrict__ Vt,
                float* __restrict__ out) {
  extern __shared__ char smem[];
  int bx, by, bz; swz_xy(bx, by, bz);
  const int row0 = by * 256;  // q
  const int col0 = bx * 128;  // d
  f32x4 acc[4][4] = {};
  gemm128_core(Pb + (size_t)bz * SS * SS + (size_t)row0 * SS,
               Vt + (size_t)bz * DD * SS + (size_t)col0 * SS,
               SS, 64, smem, acc);

  float* C = out + (size_t)bz * SS * DD;
  const int lane = threadIdx.x & 63, wave = threadIdx.x >> 6;
  const int wm = wave >> 1, wn = wave & 1;
#pragma unroll
  for (int m = 0; m < 4; ++m)
#pragma unroll
    for (int n = 0; n < 4; ++n) {
      int col = col0 + wn * 64 + n * 16 + (lane & 15);
      int rowb = row0 + wm * 64 + m * 16 + (lane >> 4) * 4;
#pragma unroll
      for (int j = 0; j < 4; ++j)
        __builtin_nontemporal_store(acc[m][n][j], &C[(size_t)(rowb + j) * DD + col]);
    }
}

// ---------------- fused casts: x, Wq, Wk, Wv -> fp16 in one dispatch ------------
__global__ __launch_bounds__(256)
void split_all(const float* __restrict__ x, const float* __restrict__ Wq,
               const float* __restrict__ Wk, const float* __restrict__ Wv,
               f16* __restrict__ xh, f16* __restrict__ wqh,
               f16* __restrict__ wkh, f16* __restrict__ wvh) {
  const int b = blockIdx.x, tid = threadIdx.x;
  const float* in; f16* hi; int nv, rb, nb;
  if (b < 1536)      { in = x;  hi = xh;  nv = (MROWS * DD) >> 2; rb = b;        nb = 1536; }
  else if (b < 1792) { in = Wq; hi = wqh; nv = (DD * DD) >> 2;    rb = b - 1536; nb = 256; }
  else if (b < 2048) { in = Wk; hi = wkh; nv = (DD * DD) >> 2;    rb = b - 1792; nb = 256; }
  else               { in = Wv; hi = wvh; nv = (DD * DD) >> 2;    rb = b - 2048; nb = 256; }
  for (int i = rb * 256 + tid; i < nv; i += nb * 256) {
    f32x4 v = *(const f32x4*)(in + (size_t)i * 4);
    f16x4 h;
#pragma unroll
    for (int e = 0; e < 4; ++e) h[e] = (f16)v[e];
    *(f16x4*)(hi + (size_t)i * 4) = h;
  }
}

// ---------------- softmax + dropout (fp16 out, NT loads) ----------------
__global__ __launch_bounds__(256)
void softmax_dropout(const float* __restrict__ Sf, const float* __restrict__ U,
                     f16* __restrict__ P) {
  __shared__ float red[4];
  const size_t row = blockIdx.x;
  const float* s = Sf + row * SS;
  const float* u = U + row * SS;
  f16* p = P + row * SS;
  const int tid = threadIdx.x, lane = tid & 63, wave = tid >> 6;

  f32x4 v[4];
  float m = -3.0e38f;
#pragma unroll
  for (int j = 0; j < 4; ++j) {
    v[j] = __builtin_nontemporal_load((const f32x4*)(s + (size_t)(j * 256 + tid) * 4));
#pragma unroll
    for (int e = 0; e < 4; ++e) m = fmaxf(m, v[j][e]);
  }
#pragma unroll
  for (int o = 32; o > 0; o >>= 1) m = fmaxf(m, __shfl_xor(m, o));
  if (lane == 0) red[wave] = m;
  __syncthreads();
  m = fmaxf(fmaxf(red[0], red[1]), fmaxf(red[2], red[3]));

  float sum = 0.0f;
#pragma unroll
  for (int j = 0; j < 4; ++j)
#pragma unroll
    for (int e = 0; e < 4; ++e) { float ex = __expf(v[j][e] - m); v[j][e] = ex; sum += ex; }
#pragma unroll
  for (int o = 32; o > 0; o >>= 1) sum += __shfl_xor(sum, o);
  __syncthreads();
  if (lane == 0) red[wave] = sum;
  __syncthreads();
  sum = red[0] + red[1] + red[2] + red[3];
  const float scale = 1.25f / sum;

#pragma unroll
  for (int j = 0; j < 4; ++j) {
    f32x4 uu = __builtin_nontemporal_load((const f32x4*)(u + (size_t)(j * 256 + tid) * 4));
    f16x4 out;
#pragma unroll
    for (int e = 0; e < 4; ++e)
      out[e] = (f16)((uu[e] >= 0.2f) ? v[j][e] * scale : 0.0f);
    *(f16x4*)(p + (size_t)(j * 256 + tid) * 4) = out;
  }
}

// ---------------- launcher ----------------
extern "C" void kernel_launch(void* const* d_in, const int* in_sizes, int n_in,
                              void* d_out, int out_size, void* d_ws, size_t ws_size,
                              hipStream_t stream) {
  if (ws_size < WS_NEEDED) return;

  const float* x  = (const float*)d_in[0];
  const float* Wq = (const float*)d_in[1];
  const float* bq = (const float*)d_in[2];
  const float* Wk = (const float*)d_in[3];
  const float* bk = (const float*)d_in[4];
  const float* Wv = (const float*)d_in[5];
  const float* bv = (const float*)d_in[6];
  const float* du = (const float*)d_in[7];

  char* ws = (char*)d_ws;
  f16*   Vt  = (f16*)(ws + O_VT);
  f16*   Pb  = (f16*)(ws + O_ATTN);
  f16*   Q   = (f16*)(ws + O_Q);
  f16*   K   = (f16*)(ws + O_K);
  float* Sf  = (float*)(ws + O_S);
  f16*   xh  = (f16*)(ws + O_XH);
  f16*   wqh = (f16*)(ws + O_WQH);
  f16*   wkh = (f16*)(ws + O_WKH);
  f16*   wvh = (f16*)(ws + O_WVH);
  float* out = (float*)d_out;

  hipFuncSetAttribute((const void*)gemm_sc128,
                      hipFuncAttributeMaxDynamicSharedMemorySize, 131072);
  hipFuncSetAttribute((const void*)gemm_projvt128,
                      hipFuncAttributeMaxDynamicSharedMemorySize, 131072);
  hipFuncSetAttribute((const void*)gemm_pv128,
                      hipFuncAttributeMaxDynamicSharedMemorySize, 131072);

  // 1) casts (one dispatch)
  split_all<<<2304, 256, 0, stream>>>(x, Wq, Wk, Wv, xh, wqh, wkh, wvh);

  // 2) Q+K projections + Vt, merged (768 blocks = 3 clean block-waves)
  gemm_projvt128<<<768, 512, 131072, stream>>>(
      xh, wqh, wkh, wvh, bq, bk, bv, Q, K, Vt);

  // 3) scores = Q K^T (1024 blocks, supertiled XCD map)
  gemm_sc128<<<dim3(32, 16, BB), 512, 131072, stream>>>(Q, K, Sf);

  // 4) softmax + dropout -> attn fp16
  softmax_dropout<<<MROWS, 256, 0, stream>>>(Sf, du, Pb);

  // 5) out = attn @ V (256 blocks)
  gemm_pv128<<<dim3(DD / 128, SS / 256, BB), 512, 131072, stream>>>(Pb, Vt, out);
}

// Round 14
// 257.735 us; speedup vs baseline: 1.0060x; 1.0060x over previous
//
#include <hip/hip_runtime.h>

typedef float    f32x4 __attribute__((ext_vector_type(4)));
typedef _Float16 f16x8 __attribute__((ext_vector_type(8)));
typedef _Float16 f16x4 __attribute__((ext_vector_type(4)));
typedef _Float16 f16;

#define DEVFN static __device__ __forceinline__

constexpr int BB = 2, SS = 4096, DD = 1024;
constexpr int MROWS = BB * SS; // 8192

// ---------------- workspace layout (bytes) ----------------
constexpr size_t SZ_QK   = (size_t)MROWS * DD * 2;
constexpr size_t SZ_VT   = (size_t)BB * DD * SS * 2;
constexpr size_t SZ_ATTN = (size_t)BB * SS * SS * 2;
constexpr size_t SZ_S    = (size_t)BB * SS * SS * 4;
constexpr size_t SZ_W    = (size_t)DD * DD * 2;

constexpr size_t O_VT   = 0;
constexpr size_t O_ATTN = O_VT + SZ_VT;
constexpr size_t O_Q    = O_ATTN;            // Q fp16, dead after scores
constexpr size_t O_K    = O_Q + 2 * SZ_QK;   // K fp16, dead after scores
constexpr size_t O_S    = O_ATTN + SZ_ATTN;  // f32 scores
constexpr size_t O_XH   = O_S;               // phase-1 aliases in scores region
constexpr size_t O_WQH  = O_XH + SZ_QK;
constexpr size_t O_WKH  = O_WQH + SZ_W;
constexpr size_t O_WVH  = O_WKH + SZ_W;
constexpr size_t WS_NEEDED = SZ_VT + SZ_ATTN + SZ_S;

// ---------------- helpers ----------------
DEVFN f32x4 mfma16x16x32(f16x8 a, f16x8 b, f32x4 c) {
  return __builtin_amdgcn_mfma_f32_16x16x32_f16(a, b, c, 0, 0, 0);
}

DEVFN void gld16(const f16* g, char* l) {
  __builtin_amdgcn_global_load_lds((const __attribute__((address_space(1))) void*)g,
                                   (__attribute__((address_space(3))) void*)l, 16, 0, 0);
}

// bijective XCD-chunked block swizzle (requires total blocks % 8 == 0)
DEVFN void swz_xy(int& bx, int& by, int& bz) {
  const int gx = gridDim.x, gy = gridDim.y, gz = gridDim.z;
  const int lin = (blockIdx.z * gy + blockIdx.y) * gx + blockIdx.x;
  const int chunk = (gx * gy * gz) >> 3;
  const int nl = (lin & 7) * chunk + (lin >> 3);
  bx = nl % gx; const int r = nl / gx; by = r % gy; bz = r / gy;
}

// =====================================================================
// 256x128 8-phase GEMM core, DEEP A-prefetch (proven; projvt + pv).
// =====================================================================
DEVFN void gemm128_core(const f16* Ap, const f16* Bp, size_t ld, int NT,
                        char* smem, f32x4 (&acc)[4][4]) {
  const int tid = threadIdx.x, lane = tid & 63, wave = tid >> 6;
  const int wm = wave >> 1, wn = wave & 1;
  const size_t rk = (size_t)(tid >> 3) * ld +
                    (size_t)((((lane & 7) ^ (lane >> 3)) << 3));
  const int wvoff = wave << 10;
  const int rbA = (((wm << 6) + (lane & 15)) << 7);
  const int rbB = (((wn << 6) + (lane & 15)) << 7);
  const int cx0 = (((lane >> 4) << 4)) ^ ((lane & 7) << 4);
  const int cx1 = cx0 ^ 64;

  char* LA0 = smem;             // 32 KB
  char* LA1 = smem + 32768;     // 32 KB
  char* LA2 = smem + 65536;     // 32 KB
  char* LB0 = smem + 98304;     // 16 KB
  char* LB1 = smem + 114688;    // 16 KB

  auto stA = [&](int u, int q, char* dst) {
    int uc = (u < NT) ? u : (NT - 1);
    gld16(Ap + (size_t)(q << 6) * ld + ((size_t)uc << 6) + rk, dst + (q << 13) + wvoff);
  };
  auto stB = [&](int u, int q, char* dst) {
    int uc = (u < NT) ? u : (NT - 1);
    gld16(Bp + (size_t)(q << 6) * ld + ((size_t)uc << 6) + rk, dst + (q << 13) + wvoff);
  };
  auto rdA = [&](char* l, int m, int cx) { return *(const f16x8*)(l + rbA + (m << 11) + cx); };
  auto rdB = [&](char* l, int n, int cx) { return *(const f16x8*)(l + rbB + (n << 11) + cx); };

  f16x8 A0[2][2], B0[2][2], A0n[2][2], B0n[2][2];

  stA(0, 0, LA0); stA(0, 1, LA0); stA(0, 2, LA0); stA(0, 3, LA0);
  stB(0, 0, LB0); stB(0, 1, LB0);
  stA(1, 0, LA1); stA(1, 1, LA1); stA(1, 2, LA1); stA(1, 3, LA1);
  stB(1, 0, LB1); stB(1, 1, LB1);
  asm volatile("s_waitcnt vmcnt(6)" ::: "memory");
  __builtin_amdgcn_s_barrier();
#pragma unroll
  for (int n = 0; n < 2; ++n) { B0[n][0] = rdB(LB0, n, cx0); B0[n][1] = rdB(LB0, n, cx1); }
#pragma unroll
  for (int m = 0; m < 2; ++m) { A0[m][0] = rdA(LA0, m, cx0); A0[m][1] = rdA(LA0, m, cx1); }

  char *aC = LA0, *aN = LA1, *aN2 = LA2, *bC = LB0, *bN = LB1;

  auto tileX = [&](char* lA, char* lB, char* lAn, char* lA2, char* lBn, int t,
                   f16x8 (&a0)[2][2], f16x8 (&b0)[2][2],
                   f16x8 (&a0n)[2][2], f16x8 (&b0n)[2][2]) {
    f16x8 a1[2][2], b1[2][2];
    // ph0
#pragma unroll
    for (int n = 0; n < 2; ++n) { b1[n][0] = rdB(lB, n + 2, cx0); b1[n][1] = rdB(lB, n + 2, cx1); }
    stA(t + 2, 0, lA2); stA(t + 2, 1, lA2);
    __builtin_amdgcn_s_barrier();
    asm volatile("s_waitcnt lgkmcnt(4)" ::: "memory");
    __builtin_amdgcn_sched_barrier(0);
    __builtin_amdgcn_s_setprio(1);
#pragma unroll
    for (int m = 0; m < 2; ++m)
#pragma unroll
      for (int n = 0; n < 2; ++n) {
        acc[m][n] = mfma16x16x32(a0[m][0], b0[n][0], acc[m][n]);
        acc[m][n] = mfma16x16x32(a0[m][1], b0[n][1], acc[m][n]);
      }
    __builtin_amdgcn_s_setprio(0);
    __builtin_amdgcn_s_barrier();
    // ph1
#pragma unroll
    for (int m = 0; m < 2; ++m) { a1[m][0] = rdA(lA, m + 2, cx0); a1[m][1] = rdA(lA, m + 2, cx1); }
    stA(t + 2, 2, lA2); stA(t + 2, 3, lA2);
    asm volatile("s_waitcnt vmcnt(4)" ::: "memory");
    __builtin_amdgcn_s_barrier();
    asm volatile("s_waitcnt lgkmcnt(4)" ::: "memory");
    __builtin_amdgcn_sched_barrier(0);
    __builtin_amdgcn_s_setprio(1);
#pragma unroll
    for (int m = 0; m < 2; ++m)
#pragma unroll
      for (int n = 0; n < 2; ++n) {
        acc[m][n + 2] = mfma16x16x32(a0[m][0], b1[n][0], acc[m][n + 2]);
        acc[m][n + 2] = mfma16x16x32(a0[m][1], b1[n][1], acc[m][n + 2]);
      }
    __builtin_amdgcn_s_setprio(0);
    __builtin_amdgcn_s_barrier();
    // ph2
#pragma unroll
    for (int n = 0; n < 2; ++n) { b0n[n][0] = rdB(lBn, n, cx0); b0n[n][1] = rdB(lBn, n, cx1); }
    stB(t + 2, 0, lB); stB(t + 2, 1, lB);
    __builtin_amdgcn_s_barrier();
    asm volatile("s_waitcnt lgkmcnt(4)" ::: "memory");
    __builtin_amdgcn_sched_barrier(0);
    __builtin_amdgcn_s_setprio(1);
#pragma unroll
    for (int m = 0; m < 2; ++m)
#pragma unroll
      for (int n = 0; n < 2; ++n) {
        acc[m + 2][n] = mfma16x16x32(a1[m][0], b0[n][0], acc[m + 2][n]);
        acc[m + 2][n] = mfma16x16x32(a1[m][1], b0[n][1], acc[m + 2][n]);
      }
    __builtin_amdgcn_s_setprio(0);
    __builtin_amdgcn_s_barrier();
    // ph3
#pragma unroll
    for (int m = 0; m < 2; ++m) { a0n[m][0] = rdA(lAn, m, cx0); a0n[m][1] = rdA(lAn, m, cx1); }
    __builtin_amdgcn_s_barrier();
    asm volatile("s_waitcnt lgkmcnt(4)" ::: "memory");
    __builtin_amdgcn_sched_barrier(0);
    __builtin_amdgcn_s_setprio(1);
#pragma unroll
    for (int m = 0; m < 2; ++m)
#pragma unroll
      for (int n = 0; n < 2; ++n) {
        acc[m + 2][n + 2] = mfma16x16x32(a1[m][0], b1[n][0], acc[m + 2][n + 2]);
        acc[m + 2][n + 2] = mfma16x16x32(a1[m][1], b1[n][1], acc[m + 2][n + 2]);
      }
    __builtin_amdgcn_s_setprio(0);
    __builtin_amdgcn_s_barrier();
  };

  for (int t = 0; t < NT; t += 2) {
    tileX(aC, bC, aN, aN2, bN, t, A0, B0, A0n, B0n);
    { char* tmp = aC; aC = aN; aN = aN2; aN2 = tmp; }
    { char* tmp = bC; bC = bN; bN = tmp; }
    tileX(aC, bC, aN, aN2, bN, t + 1, A0n, B0n, A0, B0);
    { char* tmp = aC; aC = aN; aN = aN2; aN2 = tmp; }
    { char* tmp = bC; bC = bN; bN = tmp; }
  }
  asm volatile("s_waitcnt vmcnt(0)" ::: "memory");
}

// =====================================================================
// NEW: 256x256 2-phase GEMM core, BK=32 (sc only).
// Waves 2m x 4n, wave-tile 128x64. LDS: A x3 (16KB) + B x2 (16KB) = 80KB.
// Per tile: ph0 {read a1; stage A(t+2); lgkm(4); 16 MFMA a0*b; vmcnt(2); bar}
//           ph1 {read b(t+1),a0(t+1); stage B(t+2); lgkm(8); 16 MFMA a1*b; bar}
// LDS traffic 96 KB / 4.2 MF (25% less than 128-core); 2 barriers per 4.2 MF.
// Swizzle: 64-B rows, 16-B unit ^= row&3 (both staging source and reads).
// =====================================================================
DEVFN void gemm256sq_core(const f16* Ap, const f16* Bp, size_t ld, int NT,
                          char* smem, f32x4 (&acc)[8][4]) {
  const int tid = threadIdx.x, lane = tid & 63, wave = tid >> 6;
  const int wm = wave >> 2, wn = wave & 3;
  // staging: row = tid>>2, unit = tid&3, source pre-swizzled by row&3
  const size_t rk = (size_t)(tid >> 2) * ld +
                    (size_t)((((tid & 3) ^ ((tid >> 2) & 3)) << 3));
  const int wvoff = wave << 10;
  // reads: row' = (lane&15), unit = lane>>4, swizzle unit ^ (lane&3)
  const int rbA = (wm << 13) + ((lane & 15) << 6);
  const int rbB = (wn << 12) + ((lane & 15) << 6);
  const int csw = (((lane >> 4) ^ (lane & 3)) << 4);

  char* A0b = smem;             // 16 KB each
  char* A1b = smem + 16384;
  char* A2b = smem + 32768;
  char* B0b = smem + 49152;
  char* B1b = smem + 65536;

  auto stA = [&](int u, int c, char* dst) {
    int uc = (u < NT) ? u : (NT - 1);
    gld16(Ap + (size_t)(c << 7) * ld + (uc << 5) + rk, dst + (c << 13) + wvoff);
  };
  auto stB = [&](int u, int c, char* dst) {
    int uc = (u < NT) ? u : (NT - 1);
    gld16(Bp + (size_t)(c << 7) * ld + (uc << 5) + rk, dst + (c << 13) + wvoff);
  };
  auto rdA = [&](char* buf, int half, int f) {
    return *(const f16x8*)(buf + rbA + (half << 12) + (f << 10) + csw);
  };
  auto rdB = [&](char* buf, int f) {
    return *(const f16x8*)(buf + rbB + (f << 10) + csw);
  };

  f16x8 a0[4], a1[4], b[4], a0n[4], bn[4];

  // prologue: A(0),B(0),A(1),B(1); keep newest 4 in flight
  stA(0, 0, A0b); stA(0, 1, A0b);
  stB(0, 0, B0b); stB(0, 1, B0b);
  stA(1, 0, A1b); stA(1, 1, A1b);
  stB(1, 0, B1b); stB(1, 1, B1b);
  asm volatile("s_waitcnt vmcnt(4)" ::: "memory");
  __builtin_amdgcn_s_barrier();
#pragma unroll
  for (int f = 0; f < 4; ++f) a0[f] = rdA(A0b, 0, f);
#pragma unroll
  for (int f = 0; f < 4; ++f) b[f] = rdB(B0b, f);

  for (int t = 0; t < NT; ++t) {
    // ---- ph0: read a1(t); stage A(t+2); MFMA a0 x b ----
#pragma unroll
    for (int f = 0; f < 4; ++f) a1[f] = rdA(A0b, 1, f);
    stA(t + 2, 0, A2b); stA(t + 2, 1, A2b);
    asm volatile("s_waitcnt lgkmcnt(4)" ::: "memory");
    __builtin_amdgcn_sched_barrier(0);
    __builtin_amdgcn_s_setprio(1);
#pragma unroll
    for (int m = 0; m < 4; ++m)
#pragma unroll
      for (int n = 0; n < 4; ++n)
        acc[m][n] = mfma16x16x32(a0[m], b[n], acc[m][n]);
    __builtin_amdgcn_s_setprio(0);
    asm volatile("s_waitcnt vmcnt(2)" ::: "memory"); // A(t+1),B(t+1) landed
    __builtin_amdgcn_s_barrier();
    // ---- ph1: read b(t+1), a0(t+1); stage B(t+2) -> B0b; MFMA a1 x b ----
#pragma unroll
    for (int f = 0; f < 4; ++f) bn[f] = rdB(B1b, f);
#pragma unroll
    for (int f = 0; f < 4; ++f) a0n[f] = rdA(A1b, 0, f);
    stB(t + 2, 0, B0b); stB(t + 2, 1, B0b);
    asm volatile("s_waitcnt lgkmcnt(8)" ::: "memory");
    __builtin_amdgcn_sched_barrier(0);
    __builtin_amdgcn_s_setprio(1);
#pragma unroll
    for (int m = 0; m < 4; ++m)
#pragma unroll
      for (int n = 0; n < 4; ++n)
        acc[m + 4][n] = mfma16x16x32(a1[m], b[n], acc[m + 4][n]);
    __builtin_amdgcn_s_setprio(0);
    __builtin_amdgcn_s_barrier();
    // rotate buffers + registers
    { char* tmp = A0b; A0b = A1b; A1b = A2b; A2b = tmp; }
    { char* tmp = B0b; B0b = B1b; B1b = tmp; }
#pragma unroll
    for (int f = 0; f < 4; ++f) { a0[f] = a0n[f]; b[f] = bn[f]; }
  }
  asm volatile("s_waitcnt vmcnt(0)" ::: "memory");
}

// ---------------- scores = Q . K^T on the 256sq core (512 blocks) -----------
__global__ __launch_bounds__(512, 2)
void gemm_sc256(const f16* __restrict__ Q, const f16* __restrict__ Kp,
                float* __restrict__ Sf) {
  extern __shared__ char smem[];
  const int lin = (blockIdx.z * 16 + blockIdx.y) * 16 + blockIdx.x; // 0..511
  const int g = (lin & 7) * 64 + (lin >> 3);   // xcd chunks of 64
  const int bz = g >> 8;
  const int w = g & 255;
  const int st = w >> 6, s = w & 63;           // 4 supertiles of 8x8
  const int bx = (st & 1) * 8 + (s & 7);
  const int by = (st >> 1) * 8 + (s >> 3);
  const size_t zo = (size_t)bz * SS * DD;
  const int row0 = by * 256, col0 = bx * 256;
  f32x4 acc[8][4] = {};
  gemm256sq_core(Q + zo + (size_t)row0 * DD, Kp + zo + (size_t)col0 * DD,
                 DD, 32, smem, acc);

  float* C = Sf + (size_t)bz * SS * SS;
  const int lane = threadIdx.x & 63, wave = threadIdx.x >> 6;
  const int wm = wave >> 2, wn = wave & 3;
#pragma unroll
  for (int m = 0; m < 8; ++m)
#pragma unroll
    for (int n = 0; n < 4; ++n) {
      int col = col0 + wn * 64 + n * 16 + (lane & 15);
      int rowb = row0 + wm * 128 + (m >> 2) * 64 + (m & 3) * 16 + (lane >> 4) * 4;
#pragma unroll
      for (int j = 0; j < 4; ++j)
        C[(size_t)(rowb + j) * SS + col] = acc[m][n][j];
    }
}

// ---------------- merged Q/K projections + Vt (768 blocks, one dispatch) -------
__global__ __launch_bounds__(512, 2)
void gemm_projvt128(const f16* __restrict__ xh,
                    const f16* __restrict__ wqh, const f16* __restrict__ wkh,
                    const f16* __restrict__ wvh,
                    const float* __restrict__ bq, const float* __restrict__ bk,
                    const float* __restrict__ bvv,
                    f16* __restrict__ Q, f16* __restrict__ K,
                    f16* __restrict__ Vt) {
  extern __shared__ char smem[];
  const int lin = blockIdx.x;                 // 768
  const int id = (lin & 7) * 96 + (lin >> 3); // bijective xcd chunking
  const int lane = threadIdx.x & 63, wave = threadIdx.x >> 6;
  const int wm = wave >> 1, wn = wave & 1;
  f32x4 acc[4][4] = {};

  if (id < 512) {
    const int bx = id & 15, by = id >> 4;     // grid (16,32)
    const int row0 = by * 256;
    const bool isK = bx >= 8;
    const int col0 = (bx & 7) * 128;
    const f16* B0p = isK ? wkh : wqh;
    const float* bias = isK ? bk : bq;
    f16* CH = isK ? K : Q;
    gemm128_core(xh + (size_t)row0 * DD, B0p + (size_t)col0 * DD, DD, 16, smem, acc);
#pragma unroll
    for (int m = 0; m < 4; ++m)
#pragma unroll
      for (int n = 0; n < 4; ++n) {
        int col = col0 + wn * 64 + n * 16 + (lane & 15);
        float bvv2 = bias[col];
        int rowb = row0 + wm * 64 + m * 16 + (lane >> 4) * 4;
#pragma unroll
        for (int j = 0; j < 4; ++j)
          CH[(size_t)(rowb + j) * DD + col] = (f16)(acc[m][n][j] + bvv2);
      }
  } else {
    const int id2 = id - 512;                 // grid (64,4): bx over s, by over d
    const int bx = id2 & 63, by = id2 >> 6;
    const int row0 = by * 256, col0 = bx * 128;
    gemm128_core(wvh + (size_t)row0 * DD, xh + (size_t)col0 * DD, DD, 16, smem, acc);
#pragma unroll
    for (int m = 0; m < 4; ++m)
#pragma unroll
      for (int n = 0; n < 4; ++n) {
        int col = col0 + wn * 64 + n * 16 + (lane & 15);
        int batch = col >> 12, sl = col & 4095;
        int rowb = row0 + wm * 64 + m * 16 + (lane >> 4) * 4;
#pragma unroll
        for (int j = 0; j < 4; ++j) {
          float v = acc[m][n][j] + bvv[rowb + j];
          Vt[(size_t)batch * DD * SS + (size_t)(rowb + j) * SS + sl] = (f16)v;
        }
      }
  }
}

// ---------------- out = attn @ V (256 blocks) ----------------
__global__ __launch_bounds__(512, 2)
void gemm_pv128(const f16* __restrict__ Pb, const f16* __restrict__ Vt,
                float* __restrict__ out) {
  extern __shared__ char smem[];
  int bx, by, bz; swz_xy(bx, by, bz);
  const int row0 = by * 256;  // q
  const int col0 = bx * 128;  // d
  f32x4 acc[4][4] = {};
  gemm128_core(Pb + (size_t)bz * SS * SS + (size_t)row0 * SS,
               Vt + (size_t)bz * DD * SS + (size_t)col0 * SS,
               SS, 64, smem, acc);

  float* C = out + (size_t)bz * SS * DD;
  const int lane = threadIdx.x & 63, wave = threadIdx.x >> 6;
  const int wm = wave >> 1, wn = wave & 1;
#pragma unroll
  for (int m = 0; m < 4; ++m)
#pragma unroll
    for (int n = 0; n < 4; ++n) {
      int col = col0 + wn * 64 + n * 16 + (lane & 15);
      int rowb = row0 + wm * 64 + m * 16 + (lane >> 4) * 4;
#pragma unroll
      for (int j = 0; j < 4; ++j)
        __builtin_nontemporal_store(acc[m][n][j], &C[(size_t)(rowb + j) * DD + col]);
    }
}

// ---------------- fused casts: x, Wq, Wk, Wv -> fp16 in one dispatch ------------
__global__ __launch_bounds__(256)
void split_all(const float* __restrict__ x, const float* __restrict__ Wq,
               const float* __restrict__ Wk, const float* __restrict__ Wv,
               f16* __restrict__ xh, f16* __restrict__ wqh,
               f16* __restrict__ wkh, f16* __restrict__ wvh) {
  const int b = blockIdx.x, tid = threadIdx.x;
  const float* in; f16* hi; int nv, rb, nb;
  if (b < 1536)      { in = x;  hi = xh;  nv = (MROWS * DD) >> 2; rb = b;        nb = 1536; }
  else if (b < 1792) { in = Wq; hi = wqh; nv = (DD * DD) >> 2;    rb = b - 1536; nb = 256; }
  else if (b < 2048) { in = Wk; hi = wkh; nv = (DD * DD) >> 2;    rb = b - 1792; nb = 256; }
  else               { in = Wv; hi = wvh; nv = (DD * DD) >> 2;    rb = b - 2048; nb = 256; }
  for (int i = rb * 256 + tid; i < nv; i += nb * 256) {
    f32x4 v = *(const f32x4*)(in + (size_t)i * 4);
    f16x4 h;
#pragma unroll
    for (int e = 0; e < 4; ++e) h[e] = (f16)v[e];
    *(f16x4*)(hi + (size_t)i * 4) = h;
  }
}

// ---------------- softmax + dropout (fp16 out, NT loads) ----------------
__global__ __launch_bounds__(256)
void softmax_dropout(const float* __restrict__ Sf, const float* __restrict__ U,
                     f16* __restrict__ P) {
  __shared__ float red[4];
  const size_t row = blockIdx.x;
  const float* s = Sf + row * SS;
  const float* u = U + row * SS;
  f16* p = P + row * SS;
  const int tid = threadIdx.x, lane = tid & 63, wave = tid >> 6;

  f32x4 v[4];
  float m = -3.0e38f;
#pragma unroll
  for (int j = 0; j < 4; ++j) {
    v[j] = __builtin_nontemporal_load((const f32x4*)(s + (size_t)(j * 256 + tid) * 4));
#pragma unroll
    for (int e = 0; e < 4; ++e) m = fmaxf(m, v[j][e]);
  }
#pragma unroll
  for (int o = 32; o > 0; o >>= 1) m = fmaxf(m, __shfl_xor(m, o));
  if (lane == 0) red[wave] = m;
  __syncthreads();
  m = fmaxf(fmaxf(red[0], red[1]), fmaxf(red[2], red[3]));

  float sum = 0.0f;
#pragma unroll
  for (int j = 0; j < 4; ++j)
#pragma unroll
    for (int e = 0; e < 4; ++e) { float ex = __expf(v[j][e] - m); v[j][e] = ex; sum += ex; }
#pragma unroll
  for (int o = 32; o > 0; o >>= 1) sum += __shfl_xor(sum, o);
  __syncthreads();
  if (lane == 0) red[wave] = sum;
  __syncthreads();
  sum = red[0] + red[1] + red[2] + red[3];
  const float scale = 1.25f / sum;

#pragma unroll
  for (int j = 0; j < 4; ++j) {
    f32x4 uu = __builtin_nontemporal_load((const f32x4*)(u + (size_t)(j * 256 + tid) * 4));
    f16x4 out;
#pragma unroll
    for (int e = 0; e < 4; ++e)
      out[e] = (f16)((uu[e] >= 0.2f) ? v[j][e] * scale : 0.0f);
    *(f16x4*)(p + (size_t)(j * 256 + tid) * 4) = out;
  }
}

// ---------------- launcher ----------------
extern "C" void kernel_launch(void* const* d_in, const int* in_sizes, int n_in,
                              void* d_out, int out_size, void* d_ws, size_t ws_size,
                              hipStream_t stream) {
  if (ws_size < WS_NEEDED) return;

  const float* x  = (const float*)d_in[0];
  const float* Wq = (const float*)d_in[1];
  const float* bq = (const float*)d_in[2];
  const float* Wk = (const float*)d_in[3];
  const float* bk = (const float*)d_in[4];
  const float* Wv = (const float*)d_in[5];
  const float* bv = (const float*)d_in[6];
  const float* du = (const float*)d_in[7];

  char* ws = (char*)d_ws;
  f16*   Vt  = (f16*)(ws + O_VT);
  f16*   Pb  = (f16*)(ws + O_ATTN);
  f16*   Q   = (f16*)(ws + O_Q);
  f16*   K   = (f16*)(ws + O_K);
  float* Sf  = (float*)(ws + O_S);
  f16*   xh  = (f16*)(ws + O_XH);
  f16*   wqh = (f16*)(ws + O_WQH);
  f16*   wkh = (f16*)(ws + O_WKH);
  f16*   wvh = (f16*)(ws + O_WVH);
  float* out = (float*)d_out;

  hipFuncSetAttribute((const void*)gemm_sc256,
                      hipFuncAttributeMaxDynamicSharedMemorySize, 81920);
  hipFuncSetAttribute((const void*)gemm_projvt128,
                      hipFuncAttributeMaxDynamicSharedMemorySize, 131072);
  hipFuncSetAttribute((const void*)gemm_pv128,
                      hipFuncAttributeMaxDynamicSharedMemorySize, 131072);

  // 1) casts (one dispatch)
  split_all<<<2304, 256, 0, stream>>>(x, Wq, Wk, Wv, xh, wqh, wkh, wvh);

  // 2) Q+K projections + Vt, merged (768 blocks = 3 clean block-waves)
  gemm_projvt128<<<768, 512, 131072, stream>>>(
      xh, wqh, wkh, wvh, bq, bk, bv, Q, K, Vt);

  // 3) scores = Q K^T (512 blocks, 256sq 2-phase core)
  gemm_sc256<<<dim3(16, 16, BB), 512, 81920, stream>>>(Q, K, Sf);

  // 4) softmax + dropout -> attn fp16
  softmax_dropout<<<MROWS, 256, 0, stream>>>(Sf, du, Pb);

  // 5) out = attn @ V (256 blocks)
  gemm_pv128<<<dim3(DD / 128, SS / 256, BB), 512, 131072, stream>>>(Pb, Vt, out);
}

// Round 15
// 254.894 us; speedup vs baseline: 1.0172x; 1.0111x over previous
//
#include <hip/hip_runtime.h>

typedef float    f32x4 __attribute__((ext_vector_type(4)));
typedef _Float16 f16x8 __attribute__((ext_vector_type(8)));
typedef _Float16 f16x4 __attribute__((ext_vector_type(4)));
typedef _Float16 f16;

#define DEVFN static __device__ __forceinline__

constexpr int BB = 2, SS = 4096, DD = 1024;
constexpr int MROWS = BB * SS; // 8192

// ---------------- workspace layout (bytes) ----------------
constexpr size_t SZ_QK   = (size_t)MROWS * DD * 2;
constexpr size_t SZ_VT   = (size_t)BB * DD * SS * 2;
constexpr size_t SZ_ATTN = (size_t)BB * SS * SS * 2;
constexpr size_t SZ_S    = (size_t)BB * SS * SS * 4;
constexpr size_t SZ_W    = (size_t)DD * DD * 2;

constexpr size_t O_VT   = 0;
constexpr size_t O_ATTN = O_VT + SZ_VT;
constexpr size_t O_Q    = O_ATTN;            // Q fp16, dead after scores
constexpr size_t O_K    = O_Q + 2 * SZ_QK;   // K fp16, dead after scores
constexpr size_t O_S    = O_ATTN + SZ_ATTN;  // f32 scores
constexpr size_t O_XH   = O_S;               // phase-1 aliases in scores region
constexpr size_t O_WQH  = O_XH + SZ_QK;
constexpr size_t O_WKH  = O_WQH + SZ_W;
constexpr size_t O_WVH  = O_WKH + SZ_W;
constexpr size_t WS_NEEDED = SZ_VT + SZ_ATTN + SZ_S;

// ---------------- helpers ----------------
DEVFN f32x4 mfma16x16x32(f16x8 a, f16x8 b, f32x4 c) {
  return __builtin_amdgcn_mfma_f32_16x16x32_f16(a, b, c, 0, 0, 0);
}

DEVFN void gld16(const f16* g, char* l) {
  __builtin_amdgcn_global_load_lds((const __attribute__((address_space(1))) void*)g,
                                   (__attribute__((address_space(3))) void*)l, 16, 0, 0);
}

// bijective XCD-chunked block swizzle (requires total blocks % 8 == 0)
DEVFN void swz_xy(int& bx, int& by, int& bz) {
  const int gx = gridDim.x, gy = gridDim.y, gz = gridDim.z;
  const int lin = (blockIdx.z * gy + blockIdx.y) * gx + blockIdx.x;
  const int chunk = (gx * gy * gz) >> 3;
  const int nl = (lin & 7) * chunk + (lin >> 3);
  bx = nl % gx; const int r = nl / gx; by = r % gy; bz = r / gy;
}

// =====================================================================
// 256x128 8-phase GEMM core, DEEP A-prefetch (proven; projvt + pv).
// Row stride 128 B = 32 banks -> its u^=lane&7 swizzle is 2-way uniform
// (0 measured conflicts). Do not touch.
// =====================================================================
DEVFN void gemm128_core(const f16* Ap, const f16* Bp, size_t ld, int NT,
                        char* smem, f32x4 (&acc)[4][4]) {
  const int tid = threadIdx.x, lane = tid & 63, wave = tid >> 6;
  const int wm = wave >> 1, wn = wave & 1;
  const size_t rk = (size_t)(tid >> 3) * ld +
                    (size_t)((((lane & 7) ^ (lane >> 3)) << 3));
  const int wvoff = wave << 10;
  const int rbA = (((wm << 6) + (lane & 15)) << 7);
  const int rbB = (((wn << 6) + (lane & 15)) << 7);
  const int cx0 = (((lane >> 4) << 4)) ^ ((lane & 7) << 4);
  const int cx1 = cx0 ^ 64;

  char* LA0 = smem;             // 32 KB
  char* LA1 = smem + 32768;     // 32 KB
  char* LA2 = smem + 65536;     // 32 KB
  char* LB0 = smem + 98304;     // 16 KB
  char* LB1 = smem + 114688;    // 16 KB

  auto stA = [&](int u, int q, char* dst) {
    int uc = (u < NT) ? u : (NT - 1);
    gld16(Ap + (size_t)(q << 6) * ld + ((size_t)uc << 6) + rk, dst + (q << 13) + wvoff);
  };
  auto stB = [&](int u, int q, char* dst) {
    int uc = (u < NT) ? u : (NT - 1);
    gld16(Bp + (size_t)(q << 6) * ld + ((size_t)uc << 6) + rk, dst + (q << 13) + wvoff);
  };
  auto rdA = [&](char* l, int m, int cx) { return *(const f16x8*)(l + rbA + (m << 11) + cx); };
  auto rdB = [&](char* l, int n, int cx) { return *(const f16x8*)(l + rbB + (n << 11) + cx); };

  f16x8 A0[2][2], B0[2][2], A0n[2][2], B0n[2][2];

  stA(0, 0, LA0); stA(0, 1, LA0); stA(0, 2, LA0); stA(0, 3, LA0);
  stB(0, 0, LB0); stB(0, 1, LB0);
  stA(1, 0, LA1); stA(1, 1, LA1); stA(1, 2, LA1); stA(1, 3, LA1);
  stB(1, 0, LB1); stB(1, 1, LB1);
  asm volatile("s_waitcnt vmcnt(6)" ::: "memory");
  __builtin_amdgcn_s_barrier();
#pragma unroll
  for (int n = 0; n < 2; ++n) { B0[n][0] = rdB(LB0, n, cx0); B0[n][1] = rdB(LB0, n, cx1); }
#pragma unroll
  for (int m = 0; m < 2; ++m) { A0[m][0] = rdA(LA0, m, cx0); A0[m][1] = rdA(LA0, m, cx1); }

  char *aC = LA0, *aN = LA1, *aN2 = LA2, *bC = LB0, *bN = LB1;

  auto tileX = [&](char* lA, char* lB, char* lAn, char* lA2, char* lBn, int t,
                   f16x8 (&a0)[2][2], f16x8 (&b0)[2][2],
                   f16x8 (&a0n)[2][2], f16x8 (&b0n)[2][2]) {
    f16x8 a1[2][2], b1[2][2];
    // ph0
#pragma unroll
    for (int n = 0; n < 2; ++n) { b1[n][0] = rdB(lB, n + 2, cx0); b1[n][1] = rdB(lB, n + 2, cx1); }
    stA(t + 2, 0, lA2); stA(t + 2, 1, lA2);
    __builtin_amdgcn_s_barrier();
    asm volatile("s_waitcnt lgkmcnt(4)" ::: "memory");
    __builtin_amdgcn_sched_barrier(0);
    __builtin_amdgcn_s_setprio(1);
#pragma unroll
    for (int m = 0; m < 2; ++m)
#pragma unroll
      for (int n = 0; n < 2; ++n) {
        acc[m][n] = mfma16x16x32(a0[m][0], b0[n][0], acc[m][n]);
        acc[m][n] = mfma16x16x32(a0[m][1], b0[n][1], acc[m][n]);
      }
    __builtin_amdgcn_s_setprio(0);
    __builtin_amdgcn_s_barrier();
    // ph1
#pragma unroll
    for (int m = 0; m < 2; ++m) { a1[m][0] = rdA(lA, m + 2, cx0); a1[m][1] = rdA(lA, m + 2, cx1); }
    stA(t + 2, 2, lA2); stA(t + 2, 3, lA2);
    asm volatile("s_waitcnt vmcnt(4)" ::: "memory");
    __builtin_amdgcn_s_barrier();
    asm volatile("s_waitcnt lgkmcnt(4)" ::: "memory");
    __builtin_amdgcn_sched_barrier(0);
    __builtin_amdgcn_s_setprio(1);
#pragma unroll
    for (int m = 0; m < 2; ++m)
#pragma unroll
      for (int n = 0; n < 2; ++n) {
        acc[m][n + 2] = mfma16x16x32(a0[m][0], b1[n][0], acc[m][n + 2]);
        acc[m][n + 2] = mfma16x16x32(a0[m][1], b1[n][1], acc[m][n + 2]);
      }
    __builtin_amdgcn_s_setprio(0);
    __builtin_amdgcn_s_barrier();
    // ph2
#pragma unroll
    for (int n = 0; n < 2; ++n) { b0n[n][0] = rdB(lBn, n, cx0); b0n[n][1] = rdB(lBn, n, cx1); }
    stB(t + 2, 0, lB); stB(t + 2, 1, lB);
    __builtin_amdgcn_s_barrier();
    asm volatile("s_waitcnt lgkmcnt(4)" ::: "memory");
    __builtin_amdgcn_sched_barrier(0);
    __builtin_amdgcn_s_setprio(1);
#pragma unroll
    for (int m = 0; m < 2; ++m)
#pragma unroll
      for (int n = 0; n < 2; ++n) {
        acc[m + 2][n] = mfma16x16x32(a1[m][0], b0[n][0], acc[m + 2][n]);
        acc[m + 2][n] = mfma16x16x32(a1[m][1], b0[n][1], acc[m + 2][n]);
      }
    __builtin_amdgcn_s_setprio(0);
    __builtin_amdgcn_s_barrier();
    // ph3
#pragma unroll
    for (int m = 0; m < 2; ++m) { a0n[m][0] = rdA(lAn, m, cx0); a0n[m][1] = rdA(lAn, m, cx1); }
    __builtin_amdgcn_s_barrier();
    asm volatile("s_waitcnt lgkmcnt(4)" ::: "memory");
    __builtin_amdgcn_sched_barrier(0);
    __builtin_amdgcn_s_setprio(1);
#pragma unroll
    for (int m = 0; m < 2; ++m)
#pragma unroll
      for (int n = 0; n < 2; ++n) {
        acc[m + 2][n + 2] = mfma16x16x32(a1[m][0], b1[n][0], acc[m + 2][n + 2]);
        acc[m + 2][n + 2] = mfma16x16x32(a1[m][1], b1[n][1], acc[m + 2][n + 2]);
      }
    __builtin_amdgcn_s_setprio(0);
    __builtin_amdgcn_s_barrier();
  };

  for (int t = 0; t < NT; t += 2) {
    tileX(aC, bC, aN, aN2, bN, t, A0, B0, A0n, B0n);
    { char* tmp = aC; aC = aN; aN = aN2; aN2 = tmp; }
    { char* tmp = bC; bC = bN; bN = tmp; }
    tileX(aC, bC, aN, aN2, bN, t + 1, A0n, B0n, A0, B0);
    { char* tmp = aC; aC = aN; aN = aN2; aN2 = tmp; }
    { char* tmp = bC; bC = bN; bN = tmp; }
  }
  asm volatile("s_waitcnt vmcnt(0)" ::: "memory");
}

// =====================================================================
// 256x256 2-phase GEMM core, BK=32 (sc only).
// SWIZZLE FIX (R15): rows are 64 B (16-bank stride), so bank-base =
// 16*(row&1) + 4*unit. The old unit^=(row&3) collapsed even rows onto
// 2 of 4 unit-slots -> 4-way conflict (6.4M measured). New unit ^=
// (row>>1)&3 covers each slot exactly twice -> 2-way = free.
// Applied identically to staging source (rk) and reads (csw).
// =====================================================================
DEVFN void gemm256sq_core(const f16* Ap, const f16* Bp, size_t ld, int NT,
                          char* smem, f32x4 (&acc)[8][4]) {
  const int tid = threadIdx.x, lane = tid & 63, wave = tid >> 6;
  const int wm = wave >> 2, wn = wave & 3;
  // staging: row = tid>>2, unit = tid&3; source pre-swizzled by (row>>1)&3
  const size_t rk = (size_t)(tid >> 2) * ld +
                    (size_t)((((tid & 3) ^ ((tid >> 3) & 3)) << 3));
  const int wvoff = wave << 10;
  // reads: row = lane&15 (mod 16 within group); unit = lane>>4, ^ (row>>1)&3
  const int rbA = (wm << 13) + ((lane & 15) << 6);
  const int rbB = (wn << 12) + ((lane & 15) << 6);
  const int csw = (((lane >> 4) ^ ((lane >> 1) & 3)) << 4);

  char* A0b = smem;             // 16 KB each
  char* A1b = smem + 16384;
  char* A2b = smem + 32768;
  char* B0b = smem + 49152;
  char* B1b = smem + 65536;

  auto stA = [&](int u, int c, char* dst) {
    int uc = (u < NT) ? u : (NT - 1);
    gld16(Ap + (size_t)(c << 7) * ld + (uc << 5) + rk, dst + (c << 13) + wvoff);
  };
  auto stB = [&](int u, int c, char* dst) {
    int uc = (u < NT) ? u : (NT - 1);
    gld16(Bp + (size_t)(c << 7) * ld + (uc << 5) + rk, dst + (c << 13) + wvoff);
  };
  auto rdA = [&](char* buf, int half, int f) {
    return *(const f16x8*)(buf + rbA + (half << 12) + (f << 10) + csw);
  };
  auto rdB = [&](char* buf, int f) {
    return *(const f16x8*)(buf + rbB + (f << 10) + csw);
  };

  f16x8 a0[4], a1[4], b[4], a0n[4], bn[4];

  // prologue: A(0),B(0),A(1),B(1); keep newest 4 in flight
  stA(0, 0, A0b); stA(0, 1, A0b);
  stB(0, 0, B0b); stB(0, 1, B0b);
  stA(1, 0, A1b); stA(1, 1, A1b);
  stB(1, 0, B1b); stB(1, 1, B1b);
  asm volatile("s_waitcnt vmcnt(4)" ::: "memory");
  __builtin_amdgcn_s_barrier();
#pragma unroll
  for (int f = 0; f < 4; ++f) a0[f] = rdA(A0b, 0, f);
#pragma unroll
  for (int f = 0; f < 4; ++f) b[f] = rdB(B0b, f);

  for (int t = 0; t < NT; ++t) {
    // ---- ph0: read a1(t); stage A(t+2); MFMA a0 x b ----
#pragma unroll
    for (int f = 0; f < 4; ++f) a1[f] = rdA(A0b, 1, f);
    stA(t + 2, 0, A2b); stA(t + 2, 1, A2b);
    asm volatile("s_waitcnt lgkmcnt(4)" ::: "memory");
    __builtin_amdgcn_sched_barrier(0);
    __builtin_amdgcn_s_setprio(1);
#pragma unroll
    for (int m = 0; m < 4; ++m)
#pragma unroll
      for (int n = 0; n < 4; ++n)
        acc[m][n] = mfma16x16x32(a0[m], b[n], acc[m][n]);
    __builtin_amdgcn_s_setprio(0);
    asm volatile("s_waitcnt vmcnt(2)" ::: "memory"); // A(t+1),B(t+1) landed
    __builtin_amdgcn_s_barrier();
    // ---- ph1: read b(t+1), a0(t+1); stage B(t+2) -> B0b; MFMA a1 x b ----
#pragma unroll
    for (int f = 0; f < 4; ++f) bn[f] = rdB(B1b, f);
#pragma unroll
    for (int f = 0; f < 4; ++f) a0n[f] = rdA(A1b, 0, f);
    stB(t + 2, 0, B0b); stB(t + 2, 1, B0b);
    asm volatile("s_waitcnt lgkmcnt(8)" ::: "memory");
    __builtin_amdgcn_sched_barrier(0);
    __builtin_amdgcn_s_setprio(1);
#pragma unroll
    for (int m = 0; m < 4; ++m)
#pragma unroll
      for (int n = 0; n < 4; ++n)
        acc[m + 4][n] = mfma16x16x32(a1[m], b[n], acc[m + 4][n]);
    __builtin_amdgcn_s_setprio(0);
    __builtin_amdgcn_s_barrier();
    // rotate buffers + registers
    { char* tmp = A0b; A0b = A1b; A1b = A2b; A2b = tmp; }
    { char* tmp = B0b; B0b = B1b; B1b = tmp; }
#pragma unroll
    for (int f = 0; f < 4; ++f) { a0[f] = a0n[f]; b[f] = bn[f]; }
  }
  asm volatile("s_waitcnt vmcnt(0)" ::: "memory");
}

// ---------------- scores = Q . K^T on the 256sq core (512 blocks) -----------
__global__ __launch_bounds__(512, 2)
void gemm_sc256(const f16* __restrict__ Q, const f16* __restrict__ Kp,
                float* __restrict__ Sf) {
  extern __shared__ char smem[];
  const int lin = (blockIdx.z * 16 + blockIdx.y) * 16 + blockIdx.x; // 0..511
  const int g = (lin & 7) * 64 + (lin >> 3);   // xcd chunks of 64
  const int bz = g >> 8;
  const int w = g & 255;
  const int st = w >> 6, s = w & 63;           // 4 supertiles of 8x8
  const int bx = (st & 1) * 8 + (s & 7);
  const int by = (st >> 1) * 8 + (s >> 3);
  const size_t zo = (size_t)bz * SS * DD;
  const int row0 = by * 256, col0 = bx * 256;
  f32x4 acc[8][4] = {};
  gemm256sq_core(Q + zo + (size_t)row0 * DD, Kp + zo + (size_t)col0 * DD,
                 DD, 32, smem, acc);

  float* C = Sf + (size_t)bz * SS * SS;
  const int lane = threadIdx.x & 63, wave = threadIdx.x >> 6;
  const int wm = wave >> 2, wn = wave & 3;
#pragma unroll
  for (int m = 0; m < 8; ++m)
#pragma unroll
    for (int n = 0; n < 4; ++n) {
      int col = col0 + wn * 64 + n * 16 + (lane & 15);
      int rowb = row0 + wm * 128 + (m >> 2) * 64 + (m & 3) * 16 + (lane >> 4) * 4;
#pragma unroll
      for (int j = 0; j < 4; ++j)
        C[(size_t)(rowb + j) * SS + col] = acc[m][n][j];
    }
}

// ---------------- merged Q/K projections + Vt (768 blocks, one dispatch) -------
__global__ __launch_bounds__(512, 2)
void gemm_projvt128(const f16* __restrict__ xh,
                    const f16* __restrict__ wqh, const f16* __restrict__ wkh,
                    const f16* __restrict__ wvh,
                    const float* __restrict__ bq, const float* __restrict__ bk,
                    const float* __restrict__ bvv,
                    f16* __restrict__ Q, f16* __restrict__ K,
                    f16* __restrict__ Vt) {
  extern __shared__ char smem[];
  const int lin = blockIdx.x;                 // 768
  const int id = (lin & 7) * 96 + (lin >> 3); // bijective xcd chunking
  const int lane = threadIdx.x & 63, wave = threadIdx.x >> 6;
  const int wm = wave >> 1, wn = wave & 1;
  f32x4 acc[4][4] = {};

  if (id < 512) {
    const int bx = id & 15, by = id >> 4;     // grid (16,32)
    const int row0 = by * 256;
    const bool isK = bx >= 8;
    const int col0 = (bx & 7) * 128;
    const f16* B0p = isK ? wkh : wqh;
    const float* bias = isK ? bk : bq;
    f16* CH = isK ? K : Q;
    gemm128_core(xh + (size_t)row0 * DD, B0p + (size_t)col0 * DD, DD, 16, smem, acc);
#pragma unroll
    for (int m = 0; m < 4; ++m)
#pragma unroll
      for (int n = 0; n < 4; ++n) {
        int col = col0 + wn * 64 + n * 16 + (lane & 15);
        float bvv2 = bias[col];
        int rowb = row0 + wm * 64 + m * 16 + (lane >> 4) * 4;
#pragma unroll
        for (int j = 0; j < 4; ++j)
          CH[(size_t)(rowb + j) * DD + col] = (f16)(acc[m][n][j] + bvv2);
      }
  } else {
    const int id2 = id - 512;                 // grid (64,4): bx over s, by over d
    const int bx = id2 & 63, by = id2 >> 6;
    const int row0 = by * 256, col0 = bx * 128;
    gemm128_core(wvh + (size_t)row0 * DD, xh + (size_t)col0 * DD, DD, 16, smem, acc);
#pragma unroll
    for (int m = 0; m < 4; ++m)
#pragma unroll
      for (int n = 0; n < 4; ++n) {
        int col = col0 + wn * 64 + n * 16 + (lane & 15);
        int batch = col >> 12, sl = col & 4095;
        int rowb = row0 + wm * 64 + m * 16 + (lane >> 4) * 4;
#pragma unroll
        for (int j = 0; j < 4; ++j) {
          float v = acc[m][n][j] + bvv[rowb + j];
          Vt[(size_t)batch * DD * SS + (size_t)(rowb + j) * SS + sl] = (f16)v;
        }
      }
  }
}

// ---------------- out = attn @ V (256 blocks) ----------------
__global__ __launch_bounds__(512, 2)
void gemm_pv128(const f16* __restrict__ Pb, const f16* __restrict__ Vt,
                float* __restrict__ out) {
  extern __shared__ char smem[];
  int bx, by, bz; swz_xy(bx, by, bz);
  const int row0 = by * 256;  // q
  const int col0 = bx * 128;  // d
  f32x4 acc[4][4] = {};
  gemm128_core(Pb + (size_t)bz * SS * SS + (size_t)row0 * SS,
               Vt + (size_t)bz * DD * SS + (size_t)col0 * SS,
               SS, 64, smem, acc);

  float* C = out + (size_t)bz * SS * DD;
  const int lane = threadIdx.x & 63, wave = threadIdx.x >> 6;
  const int wm = wave >> 1, wn = wave & 1;
#pragma unroll
  for (int m = 0; m < 4; ++m)
#pragma unroll
    for (int n = 0; n < 4; ++n) {
      int col = col0 + wn * 64 + n * 16 + (lane & 15);
      int rowb = row0 + wm * 64 + m * 16 + (lane >> 4) * 4;
#pragma unroll
      for (int j = 0; j < 4; ++j)
        __builtin_nontemporal_store(acc[m][n][j], &C[(size_t)(rowb + j) * DD + col]);
    }
}

// ---------------- fused casts: x, Wq, Wk, Wv -> fp16 in one dispatch ------------
__global__ __launch_bounds__(256)
void split_all(const float* __restrict__ x, const float* __restrict__ Wq,
               const float* __restrict__ Wk, const float* __restrict__ Wv,
               f16* __restrict__ xh, f16* __restrict__ wqh,
               f16* __restrict__ wkh, f16* __restrict__ wvh) {
  const int b = blockIdx.x, tid = threadIdx.x;
  const float* in; f16* hi; int nv, rb, nb;
  if (b < 1536)      { in = x;  hi = xh;  nv = (MROWS * DD) >> 2; rb = b;        nb = 1536; }
  else if (b < 1792) { in = Wq; hi = wqh; nv = (DD * DD) >> 2;    rb = b - 1536; nb = 256; }
  else if (b < 2048) { in = Wk; hi = wkh; nv = (DD * DD) >> 2;    rb = b - 1792; nb = 256; }
  else               { in = Wv; hi = wvh; nv = (DD * DD) >> 2;    rb = b - 2048; nb = 256; }
  for (int i = rb * 256 + tid; i < nv; i += nb * 256) {
    f32x4 v = *(const f32x4*)(in + (size_t)i * 4);
    f16x4 h;
#pragma unroll
    for (int e = 0; e < 4; ++e) h[e] = (f16)v[e];
    *(f16x4*)(hi + (size_t)i * 4) = h;
  }
}

// ---------------- softmax + dropout (fp16 out, NT loads) ----------------
__global__ __launch_bounds__(256)
void softmax_dropout(const float* __restrict__ Sf, const float* __restrict__ U,
                     f16* __restrict__ P) {
  __shared__ float red[4];
  const size_t row = blockIdx.x;
  const float* s = Sf + row * SS;
  const float* u = U + row * SS;
  f16* p = P + row * SS;
  const int tid = threadIdx.x, lane = tid & 63, wave = tid >> 6;

  f32x4 v[4];
  float m = -3.0e38f;
#pragma unroll
  for (int j = 0; j < 4; ++j) {
    v[j] = __builtin_nontemporal_load((const f32x4*)(s + (size_t)(j * 256 + tid) * 4));
#pragma unroll
    for (int e = 0; e < 4; ++e) m = fmaxf(m, v[j][e]);
  }
#pragma unroll
  for (int o = 32; o > 0; o >>= 1) m = fmaxf(m, __shfl_xor(m, o));
  if (lane == 0) red[wave] = m;
  __syncthreads();
  m = fmaxf(fmaxf(red[0], red[1]), fmaxf(red[2], red[3]));

  float sum = 0.0f;
#pragma unroll
  for (int j = 0; j < 4; ++j)
#pragma unroll
    for (int e = 0; e < 4; ++e) { float ex = __expf(v[j][e] - m); v[j][e] = ex; sum += ex; }
#pragma unroll
  for (int o = 32; o > 0; o >>= 1) sum += __shfl_xor(sum, o);
  __syncthreads();
  if (lane == 0) red[wave] = sum;
  __syncthreads();
  sum = red[0] + red[1] + red[2] + red[3];
  const float scale = 1.25f / sum;

#pragma unroll
  for (int j = 0; j < 4; ++j) {
    f32x4 uu = __builtin_nontemporal_load((const f32x4*)(u + (size_t)(j * 256 + tid) * 4));
    f16x4 out;
#pragma unroll
    for (int e = 0; e < 4; ++e)
      out[e] = (f16)((uu[e] >= 0.2f) ? v[j][e] * scale : 0.0f);
    *(f16x4*)(p + (size_t)(j * 256 + tid) * 4) = out;
  }
}

// ---------------- launcher ----------------
extern "C" void kernel_launch(void* const* d_in, const int* in_sizes, int n_in,
                              void* d_out, int out_size, void* d_ws, size_t ws_size,
                              hipStream_t stream) {
  if (ws_size < WS_NEEDED) return;

  const float* x  = (const float*)d_in[0];
  const float* Wq = (const float*)d_in[1];
  const float* bq = (const float*)d_in[2];
  const float* Wk = (const float*)d_in[3];
  const float* bk = (const float*)d_in[4];
  const float* Wv = (const float*)d_in[5];
  const float* bv = (const float*)d_in[6];
  const float* du = (const float*)d_in[7];

  char* ws = (char*)d_ws;
  f16*   Vt  = (f16*)(ws + O_VT);
  f16*   Pb  = (f16*)(ws + O_ATTN);
  f16*   Q   = (f16*)(ws + O_Q);
  f16*   K   = (f16*)(ws + O_K);
  float* Sf  = (float*)(ws + O_S);
  f16*   xh  = (f16*)(ws + O_XH);
  f16*   wqh = (f16*)(ws + O_WQH);
  f16*   wkh = (f16*)(ws + O_WKH);
  f16*   wvh = (f16*)(ws + O_WVH);
  float* out = (float*)d_out;

  hipFuncSetAttribute((const void*)gemm_sc256,
                      hipFuncAttributeMaxDynamicSharedMemorySize, 81920);
  hipFuncSetAttribute((const void*)gemm_projvt128,
                      hipFuncAttributeMaxDynamicSharedMemorySize, 131072);
  hipFuncSetAttribute((const void*)gemm_pv128,
                      hipFuncAttributeMaxDynamicSharedMemorySize, 131072);

  // 1) casts (one dispatch)
  split_all<<<2304, 256, 0, stream>>>(x, Wq, Wk, Wv, xh, wqh, wkh, wvh);

  // 2) Q+K projections + Vt, merged (768 blocks = 3 clean block-waves)
  gemm_projvt128<<<768, 512, 131072, stream>>>(
      xh, wqh, wkh, wvh, bq, bk, bv, Q, K, Vt);

  // 3) scores = Q K^T (512 blocks, 256sq 2-phase core, fixed swizzle)
  gemm_sc256<<<dim3(16, 16, BB), 512, 81920, stream>>>(Q, K, Sf);

  // 4) softmax + dropout -> attn fp16
  softmax_dropout<<<MROWS, 256, 0, stream>>>(Sf, du, Pb);

  // 5) out = attn @ V (256 blocks)
  gemm_pv128<<<dim3(DD / 128, SS / 256, BB), 512, 131072, stream>>>(Pb, Vt, out);
}